// Round 1
// baseline (1822.202 us; speedup 1.0000x reference)
//
#include <hip/hip_runtime.h>
#include <hip/hip_bf16.h>
#include <stdint.h>

typedef __bf16 bf16_t;
typedef bf16_t bf16x8 __attribute__((ext_vector_type(8)));
typedef float  f32x4  __attribute__((ext_vector_type(4)));

// ---------------- async global->LDS (16B per lane) ----------------
__device__ __forceinline__ void g2l16(const void* gp, void* lp) {
  __builtin_amdgcn_global_load_lds(
      (const __attribute__((address_space(1))) unsigned int*)(uintptr_t)gp,
      (__attribute__((address_space(3))) unsigned int*)(uint32_t)(uintptr_t)lp,
      16, 0, 0);
}

// ---------------- embed: h[i] = x_emb1[x[i,0]] + x_emb2[x[i,1]] ----------------
__global__ void embed_kernel(const int* __restrict__ x, const float* __restrict__ e1,
                             const float* __restrict__ e2, bf16_t* __restrict__ h, int N) {
  const int w = (blockIdx.x * blockDim.x + threadIdx.x) >> 6;
  const int lane = threadIdx.x & 63;
  if (w >= N || lane >= 40) return;
  const int t0 = x[2 * w], t1 = x[2 * w + 1];
  const int co = lane * 8;
  f32x4 a0 = *(const f32x4*)&e1[t0 * 300 + co];
  f32x4 a1 = *(const f32x4*)&e1[t0 * 300 + co + 4];
  f32x4 b0 = *(const f32x4*)&e2[t1 * 300 + co];
  f32x4 b1 = *(const f32x4*)&e2[t1 * 300 + co + 4];
  bf16x8 o;
  #pragma unroll
  for (int j = 0; j < 8; j++) {
    float v = (j < 4) ? (a0[j] + b0[j]) : (a1[j - 4] + b1[j - 4]);
    o[j] = (co + j < 300) ? (bf16_t)v : (bf16_t)0.f;
  }
  *(bf16x8*)&h[(size_t)w * 320 + co] = o;
}

// ---------------- CSR build ----------------
__global__ void count_deg_kernel(const int* __restrict__ ei, int* __restrict__ deg, int E) {
  int e = blockIdx.x * 256 + threadIdx.x;
  if (e < E) atomicAdd(&deg[ei[E + e]], 1);
}

__global__ void scan_partial_kernel(const int* __restrict__ deg, int* __restrict__ part, int N) {
  __shared__ int s[256];
  const int tid = threadIdx.x;
  const int idx = blockIdx.x * 256 + tid;
  s[tid] = (idx < N) ? deg[idx] : 0;
  __syncthreads();
  for (int off = 128; off > 0; off >>= 1) {
    if (tid < off) s[tid] += s[tid + off];
    __syncthreads();
  }
  if (tid == 0) part[blockIdx.x] = s[0];
}

__global__ void scan_block_kernel(int* __restrict__ part, int n) {  // n <= 1024
  __shared__ int s[1024];
  const int tid = threadIdx.x;
  const int v = (tid < n) ? part[tid] : 0;
  s[tid] = v;
  __syncthreads();
  for (int off = 1; off < 1024; off <<= 1) {
    int x = (tid >= off) ? s[tid - off] : 0;
    __syncthreads();
    s[tid] += x;
    __syncthreads();
  }
  if (tid < n) part[tid] = s[tid] - v;  // exclusive
}

__global__ void scan_final_kernel(const int* __restrict__ deg, const int* __restrict__ part,
                                  int* __restrict__ rowptr, int* __restrict__ cursor, int N, int E) {
  __shared__ int s[256];
  const int tid = threadIdx.x;
  const int idx = blockIdx.x * 256 + tid;
  const int v = (idx < N) ? deg[idx] : 0;
  s[tid] = v;
  __syncthreads();
  for (int off = 1; off < 256; off <<= 1) {
    int x = (tid >= off) ? s[tid - off] : 0;
    __syncthreads();
    s[tid] += x;
    __syncthreads();
  }
  if (idx < N) {
    int ex = s[tid] - v + part[blockIdx.x];
    rowptr[idx] = ex;
    cursor[idx] = ex;
  }
  if (idx == 0) rowptr[N] = E;
}

// pack src | (a0*3+a1)<<20
__global__ void fill_csr_kernel(const int* __restrict__ ei, const int* __restrict__ ea,
                                int* __restrict__ cursor, int* __restrict__ epack, int E) {
  int e = blockIdx.x * 256 + threadIdx.x;
  if (e >= E) return;
  int slot = atomicAdd(&cursor[ei[E + e]], 1);
  int a = ea[2 * e] * 3 + ea[2 * e + 1];
  epack[slot] = (ei[e] & 0xFFFFF) | (a << 20);
}

// ---------------- weight convert+transpose+pad to bf16 ----------------
__global__ void convert_w1_kernel(const float* __restrict__ w1, bf16_t* __restrict__ o) {
  int id = blockIdx.x * 256 + threadIdx.x;
  if (id >= 5 * 640 * 320) return;
  int k = id % 320;
  int n = (id / 320) % 640;
  int l = id / (320 * 640);
  float v = (k < 300 && n < 600) ? w1[(size_t)l * 300 * 600 + (size_t)k * 600 + n] : 0.f;
  o[id] = (bf16_t)v;
}

__global__ void convert_w2_kernel(const float* __restrict__ w2, bf16_t* __restrict__ o) {
  int id = blockIdx.x * 256 + threadIdx.x;
  if (id >= 5 * 384 * 640) return;
  int k = id % 640;
  int n = (id / 640) % 384;
  int l = id / (640 * 384);
  float v = (k < 600 && n < 300) ? w2[(size_t)l * 600 * 300 + (size_t)k * 300 + n] : 0.f;
  o[id] = (bf16_t)v;
}

// combined edge table: T12[l][a0*3+a1][col] = ee1[l][a0][col] + ee2[l][a1][col]
__global__ void build_t12_kernel(const float* __restrict__ ee1, const float* __restrict__ ee2,
                                 bf16_t* __restrict__ T12) {
  int id = blockIdx.x * 256 + threadIdx.x;
  if (id >= 5 * 21 * 320) return;
  int col = id % 320;
  int r = id / 320;
  int l = r / 21;
  int a = r % 21;
  int a0 = a / 3, a1 = a % 3;
  float v = 0.f;
  if (col < 300) v = ee1[((size_t)l * 7 + a0) * 300 + col] + ee2[((size_t)l * 3 + a1) * 300 + col];
  T12[id] = (bf16_t)v;
}

// ---------------- aggregation: wave per node, CSR gather, bf16x8 ----------------
__global__ void aggregate_kernel(const bf16_t* __restrict__ h, const int* __restrict__ rowptr,
                                 const int* __restrict__ epack, const bf16_t* __restrict__ T12L,
                                 bf16_t* __restrict__ agg, int N) {
  const int w = (blockIdx.x * blockDim.x + threadIdx.x) >> 6;
  const int lane = threadIdx.x & 63;
  if (w >= N || lane >= 40) return;
  const int co = lane * 8;
  const int beg = rowptr[w], end = rowptr[w + 1];
  float acc[8];
  {
    bf16x8 hv = *(const bf16x8*)&h[(size_t)w * 320 + co];
    bf16x8 tv = *(const bf16x8*)&T12L[12 * 320 + co];  // self loop: a0=4,a1=0
    #pragma unroll
    for (int j = 0; j < 8; j++) acc[j] = (float)hv[j] + (float)tv[j];
  }
  for (int e = beg; e < end; e++) {
    const int p = epack[e];
    const int s = p & 0xFFFFF;
    const int a = (p >> 20) & 0x1F;
    bf16x8 hv = *(const bf16x8*)&h[(size_t)s * 320 + co];
    bf16x8 tv = *(const bf16x8*)&T12L[a * 320 + co];
    #pragma unroll
    for (int j = 0; j < 8; j++) acc[j] += (float)hv[j] + (float)tv[j];
  }
  bf16x8 o;
  #pragma unroll
  for (int j = 0; j < 8; j++) o[j] = (bf16_t)acc[j];
  *(bf16x8*)&agg[(size_t)w * 320 + co] = o;
}

// ---------------- MFMA GEMM: 128x128 tile, BK=64, XOR-swizzled LDS ----------------
// Double-buffered (T3 minimum 2-phase): issue tile k+1's global_load_lds BEFORE
// computing tile k, so the __syncthreads() vmcnt(0) drain finds loads landed.
// C[m,n] = act( sum_k A[m,k]*BT[n,k] + bias[n] ).
// LDS as 16B slots: slot(row,chunk) = row*8 + (chunk ^ (row&7))  -> fragment reads
// hit bank-group ((ss*4+quad)^(ml&7)): all 8 groups covered, 2 lanes each = free.
// STATS: fused BN column stats (sum, sumsq over rows < Nvalid) from f32 acc.
template <int LDA, int LDB, int LDC, int NK, int NBIAS, bool RELU, bool STATS>
__global__ __launch_bounds__(256) void gemm_kernel(const bf16_t* __restrict__ A,
                                                   const bf16_t* __restrict__ BT,
                                                   const float* __restrict__ bias,
                                                   bf16_t* __restrict__ C,
                                                   float* __restrict__ sums,
                                                   float* __restrict__ sumsq, int Nvalid) {
  __shared__ __align__(16) bf16_t As[2][128 * 64];  // 2 x 16 KB
  __shared__ __align__(16) bf16_t Bs[2][128 * 64];  // 2 x 16 KB

  const int tid = threadIdx.x;
  const int lane = tid & 63;
  const int wave = tid >> 6;
  const int ml = lane & 15, quad = lane >> 4;
  const int wm = (wave & 1) * 64, wn = (wave >> 1) * 64;
  const int kx = ml & 7;  // fragment-read swizzle key
  const size_t bm = (size_t)blockIdx.x * 128;
  const size_t bnn = (size_t)blockIdx.y * 128;

  // staging: thread t, iter it -> slot s = it*256+t; row = it*32 + (t>>3),
  // lds chunk = t&7, global chunk = (t&7) ^ (row&7) = (t&7) ^ ((t>>3)&7)
  const int srow = tid >> 3;
  const int scg = (tid & 7) ^ (srow & 7);
  const bf16_t* ag = A + (bm + srow) * LDA + scg * 8;
  const bf16_t* bg = BT + (bnn + srow) * LDB + scg * 8;

  auto stage = [&](int buf, int kb) {
    const int kof = kb * 64;
    #pragma unroll
    for (int it = 0; it < 4; it++) {
      g2l16(ag + (size_t)it * 32 * LDA + kof, (void*)&As[buf][((size_t)it * 256 + tid) * 8]);
      g2l16(bg + (size_t)it * 32 * LDB + kof, (void*)&Bs[buf][((size_t)it * 256 + tid) * 8]);
    }
  };

  f32x4 acc[4][4];
  #pragma unroll
  for (int r = 0; r < 4; r++)
    #pragma unroll
    for (int c = 0; c < 4; c++) acc[r][c] = (f32x4){0.f, 0.f, 0.f, 0.f};

  stage(0, 0);
  __syncthreads();  // drains vmcnt(0): tile 0 resident

  int cur = 0;
  #pragma unroll
  for (int kb = 0; kb < NK; kb++) {
    if (kb + 1 < NK) stage(cur ^ 1, kb + 1);  // prefetch issues BEFORE compute
    #pragma unroll
    for (int ss = 0; ss < 2; ss++) {
      const int ck = (ss * 4 + quad) ^ kx;
      bf16x8 aF[4], bF[4];
      #pragma unroll
      for (int mf = 0; mf < 4; mf++)
        aF[mf] = *(const bf16x8*)&As[cur][((wm + mf * 16 + ml) * 8 + ck) * 8];
      #pragma unroll
      for (int nf = 0; nf < 4; nf++)
        bF[nf] = *(const bf16x8*)&Bs[cur][((wn + nf * 16 + ml) * 8 + ck) * 8];
      #pragma unroll
      for (int mf = 0; mf < 4; mf++)
        #pragma unroll
        for (int nf = 0; nf < 4; nf++)
          acc[mf][nf] = __builtin_amdgcn_mfma_f32_16x16x32_bf16(aF[mf], bF[nf], acc[mf][nf], 0, 0, 0);
    }
    __syncthreads();  // drains vmcnt(0): next tile resident; readers of cur done
    cur ^= 1;
  }

  // epilogue: C/D layout col=lane&15, row=quad*4+reg
  #pragma unroll
  for (int nf = 0; nf < 4; nf++) {
    const int colg = (int)bnn + wn + nf * 16 + ml;
    const float bv = (colg < NBIAS) ? bias[colg] : 0.f;
    float s = 0.f, sq = 0.f;
    #pragma unroll
    for (int mf = 0; mf < 4; mf++) {
      #pragma unroll
      for (int i = 0; i < 4; i++) {
        const size_t rowg = bm + wm + mf * 16 + quad * 4 + i;
        float v = acc[mf][nf][i] + bv;
        if (RELU) v = fmaxf(v, 0.f);
        C[rowg * LDC + colg] = (bf16_t)v;
        if (STATS) {
          const bool ok = rowg < (size_t)Nvalid;
          s += ok ? v : 0.f;
          sq += ok ? v * v : 0.f;
        }
      }
    }
    if (STATS) {
      // reduce across quads (lanes ml, ml+16, ml+32, ml+48 share colg)
      s += __shfl_down(s, 16);
      sq += __shfl_down(sq, 16);
      s += __shfl_down(s, 32);
      sq += __shfl_down(sq, 32);
      if (quad == 0) {
        atomicAdd(&sums[colg], s);
        atomicAdd(&sumsq[colg], sq);
      }
    }
  }
}

// ---------------- BN ----------------
__global__ void bn_params_kernel(const float* __restrict__ sums, const float* __restrict__ sumsq,
                                 const float* __restrict__ gamma, const float* __restrict__ beta,
                                 float* __restrict__ scale, float* __restrict__ shift, int N) {
  const int col = threadIdx.x;
  if (col >= 384) return;
  if (col >= 300) {  // pad cols: force h pad to 0
    scale[col] = 0.f;
    shift[col] = 0.f;
    return;
  }
  const float inv = 1.f / (float)N;
  const float mean = sums[col] * inv;
  float var = sumsq[col] * inv - mean * mean;
  if (var < 0.f) var = 0.f;
  const float sc = gamma[col] * rsqrtf(var + 1e-5f);
  scale[col] = sc;
  shift[col] = beta[col] - mean * sc;
}

// wave per node, lane<40 handles 8 cols
__global__ void bn_apply_kernel(const bf16_t* __restrict__ H2, const float* __restrict__ scale,
                                const float* __restrict__ shift, bf16_t* __restrict__ h,
                                float* __restrict__ out, int relu, int last, int N) {
  const int w = (blockIdx.x * blockDim.x + threadIdx.x) >> 6;
  const int lane = threadIdx.x & 63;
  if (w >= N || lane >= 40) return;
  const int co = lane * 8;
  bf16x8 v8 = *(const bf16x8*)&H2[(size_t)w * 384 + co];
  f32x4 s0 = *(const f32x4*)&scale[co];
  f32x4 s1 = *(const f32x4*)&scale[co + 4];
  f32x4 t0 = *(const f32x4*)&shift[co];
  f32x4 t1 = *(const f32x4*)&shift[co + 4];
  float vv[8];
  #pragma unroll
  for (int j = 0; j < 8; j++) {
    float sc = (j < 4) ? s0[j] : s1[j - 4];
    float sh = (j < 4) ? t0[j] : t1[j - 4];
    float v = (float)v8[j] * sc + sh;
    if (relu) v = fmaxf(v, 0.f);
    vv[j] = v;
  }
  if (!last) {
    bf16x8 o;
    #pragma unroll
    for (int j = 0; j < 8; j++) o[j] = (bf16_t)vv[j];
    *(bf16x8*)&h[(size_t)w * 320 + co] = o;
  } else {
    #pragma unroll
    for (int j = 0; j < 8; j++)
      if (co + j < 300) out[(size_t)w * 300 + co + j] = vv[j];
  }
}

// ---------------- launch ----------------
extern "C" void kernel_launch(void* const* d_in, const int* in_sizes, int n_in,
                              void* d_out, int out_size, void* d_ws, size_t ws_size,
                              hipStream_t stream) {
  const int* x = (const int*)d_in[0];
  const int* ei = (const int*)d_in[1];
  const int* ea = (const int*)d_in[2];
  const float* xe1 = (const float*)d_in[3];
  const float* xe2 = (const float*)d_in[4];
  const float* ee1 = (const float*)d_in[5];
  const float* ee2 = (const float*)d_in[6];
  const float* w1 = (const float*)d_in[7];
  const float* b1 = (const float*)d_in[8];
  const float* w2 = (const float*)d_in[9];
  const float* b2 = (const float*)d_in[10];
  const float* gam = (const float*)d_in[11];
  const float* bet = (const float*)d_in[12];

  const int N = in_sizes[0] / 2;   // 100000
  const int E = in_sizes[1] / 2;   // 200000
  const int Mt = (N + 127) / 128;  // 782
  const size_t Mp = (size_t)Mt * 128;

  char* p = (char*)d_ws;
  auto take = [&](size_t b) -> char* {
    char* r = p;
    p += (b + 255) & ~(size_t)255;
    return r;
  };
  bf16_t* h    = (bf16_t*)take(Mp * 320 * 2);
  bf16_t* agg  = (bf16_t*)take(Mp * 320 * 2);
  bf16_t* C1   = (bf16_t*)take(Mp * 640 * 2);
  bf16_t* H2   = (bf16_t*)take(Mp * 384 * 2);
  bf16_t* W1bT = (bf16_t*)take((size_t)5 * 640 * 320 * 2);
  bf16_t* W2bT = (bf16_t*)take((size_t)5 * 384 * 640 * 2);
  bf16_t* T12  = (bf16_t*)take((size_t)5 * 21 * 320 * 2);
  int* deg     = (int*)take((size_t)N * 4);
  int* rowptr  = (int*)take((size_t)(N + 1) * 4);
  int* cursor  = (int*)take((size_t)N * 4);
  int* part    = (int*)take(1024 * 4);
  int* epack   = (int*)take((size_t)E * 4);
  float* sums  = (float*)take(384 * 4);
  float* sumsq = (float*)take(384 * 4);
  float* scale = (float*)take(384 * 4);
  float* shift = (float*)take(384 * 4);

  // agg pad rows must be exact zeros for GEMM1 (aggregate writes rows<N only)
  hipMemsetAsync(agg, 0, Mp * 320 * 2, stream);
  hipMemsetAsync(deg, 0, (size_t)N * 4, stream);

  const int nwb = (N + 3) / 4;  // wave-per-node, 4 waves per 256-thread block
  embed_kernel<<<nwb, 256, 0, stream>>>(x, xe1, xe2, h, N);

  count_deg_kernel<<<(E + 255) / 256, 256, 0, stream>>>(ei, deg, E);
  const int nsb = (N + 255) / 256;  // 391 (<=1024 for scan_block)
  scan_partial_kernel<<<nsb, 256, 0, stream>>>(deg, part, N);
  scan_block_kernel<<<1, 1024, 0, stream>>>(part, nsb);
  scan_final_kernel<<<nsb, 256, 0, stream>>>(deg, part, rowptr, cursor, N, E);
  fill_csr_kernel<<<(E + 255) / 256, 256, 0, stream>>>(ei, ea, cursor, epack, E);

  convert_w1_kernel<<<(5 * 640 * 320 + 255) / 256, 256, 0, stream>>>(w1, W1bT);
  convert_w2_kernel<<<(5 * 384 * 640 + 255) / 256, 256, 0, stream>>>(w2, W2bT);
  build_t12_kernel<<<(5 * 21 * 320 + 255) / 256, 256, 0, stream>>>(ee1, ee2, T12);

  for (int l = 0; l < 5; l++) {
    aggregate_kernel<<<nwb, 256, 0, stream>>>(h, rowptr, epack, T12 + (size_t)l * 21 * 320,
                                              agg, N);
    // GEMM1: [Mp,320] x W1T[640,320] -> C1[Mp,640], bias b1 (600), ReLU
    gemm_kernel<320, 320, 640, 5, 600, true, false>
        <<<dim3(Mt, 5), 256, 0, stream>>>(agg, W1bT + (size_t)l * 640 * 320,
                                          b1 + (size_t)l * 600, C1, sums, sumsq, N);
    // zero stats before GEMM2's fused bn_stats epilogue
    hipMemsetAsync(sums, 0, 384 * 4, stream);
    hipMemsetAsync(sumsq, 0, 384 * 4, stream);
    // GEMM2: [Mp,640] x W2T[384,640] -> H2[Mp,384], bias b2 (300), fused col stats
    gemm_kernel<640, 640, 384, 10, 300, false, true>
        <<<dim3(Mt, 3), 256, 0, stream>>>(C1, W2bT + (size_t)l * 384 * 640,
                                          b2 + (size_t)l * 300, H2, sums, sumsq, N);
    bn_params_kernel<<<1, 384, 0, stream>>>(sums, sumsq, gam + (size_t)l * 300,
                                            bet + (size_t)l * 300, scale, shift, N);
    bn_apply_kernel<<<nwb, 256, 0, stream>>>(H2, scale, shift, h, (float*)d_out,
                                             (l < 4) ? 1 : 0, (l == 4) ? 1 : 0, N);
  }
}

// Round 2
// 1620.898 us; speedup vs baseline: 1.1242x; 1.1242x over previous
//
#include <hip/hip_runtime.h>
#include <hip/hip_bf16.h>
#include <stdint.h>

typedef __bf16 bf16_t;
typedef bf16_t bf16x8 __attribute__((ext_vector_type(8)));
typedef float  f32x4  __attribute__((ext_vector_type(4)));

// ---------------- async global->LDS (16B per lane) ----------------
__device__ __forceinline__ void g2l16(const void* gp, void* lp) {
  __builtin_amdgcn_global_load_lds(
      (const __attribute__((address_space(1))) unsigned int*)(uintptr_t)gp,
      (__attribute__((address_space(3))) unsigned int*)(uint32_t)(uintptr_t)lp,
      16, 0, 0);
}

// ---------------- embed: h[i] = x_emb1[x[i,0]] + x_emb2[x[i,1]] ----------------
__global__ void embed_kernel(const int* __restrict__ x, const float* __restrict__ e1,
                             const float* __restrict__ e2, bf16_t* __restrict__ h, int N) {
  const int w = (blockIdx.x * blockDim.x + threadIdx.x) >> 6;
  const int lane = threadIdx.x & 63;
  if (w >= N || lane >= 40) return;
  const int t0 = x[2 * w], t1 = x[2 * w + 1];
  const int co = lane * 8;
  f32x4 a0 = *(const f32x4*)&e1[t0 * 300 + co];
  f32x4 a1 = *(const f32x4*)&e1[t0 * 300 + co + 4];
  f32x4 b0 = *(const f32x4*)&e2[t1 * 300 + co];
  f32x4 b1 = *(const f32x4*)&e2[t1 * 300 + co + 4];
  bf16x8 o;
  #pragma unroll
  for (int j = 0; j < 8; j++) {
    float v = (j < 4) ? (a0[j] + b0[j]) : (a1[j - 4] + b1[j - 4]);
    o[j] = (co + j < 300) ? (bf16_t)v : (bf16_t)0.f;
  }
  *(bf16x8*)&h[(size_t)w * 320 + co] = o;
}

// ---------------- CSR build ----------------
__global__ void count_deg_kernel(const int* __restrict__ ei, int* __restrict__ deg, int E) {
  int e = blockIdx.x * 256 + threadIdx.x;
  if (e < E) atomicAdd(&deg[ei[E + e]], 1);
}

__global__ void scan_partial_kernel(const int* __restrict__ deg, int* __restrict__ part, int N) {
  __shared__ int s[256];
  const int tid = threadIdx.x;
  const int idx = blockIdx.x * 256 + tid;
  s[tid] = (idx < N) ? deg[idx] : 0;
  __syncthreads();
  for (int off = 128; off > 0; off >>= 1) {
    if (tid < off) s[tid] += s[tid + off];
    __syncthreads();
  }
  if (tid == 0) part[blockIdx.x] = s[0];
}

__global__ void scan_block_kernel(int* __restrict__ part, int n) {  // n <= 1024
  __shared__ int s[1024];
  const int tid = threadIdx.x;
  const int v = (tid < n) ? part[tid] : 0;
  s[tid] = v;
  __syncthreads();
  for (int off = 1; off < 1024; off <<= 1) {
    int x = (tid >= off) ? s[tid - off] : 0;
    __syncthreads();
    s[tid] += x;
    __syncthreads();
  }
  if (tid < n) part[tid] = s[tid] - v;  // exclusive
}

__global__ void scan_final_kernel(const int* __restrict__ deg, const int* __restrict__ part,
                                  int* __restrict__ rowptr, int* __restrict__ cursor, int N, int E) {
  __shared__ int s[256];
  const int tid = threadIdx.x;
  const int idx = blockIdx.x * 256 + tid;
  const int v = (idx < N) ? deg[idx] : 0;
  s[tid] = v;
  __syncthreads();
  for (int off = 1; off < 256; off <<= 1) {
    int x = (tid >= off) ? s[tid - off] : 0;
    __syncthreads();
    s[tid] += x;
    __syncthreads();
  }
  if (idx < N) {
    int ex = s[tid] - v + part[blockIdx.x];
    rowptr[idx] = ex;
    cursor[idx] = ex;
  }
  if (idx == 0) rowptr[N] = E;
}

// pack src | (a0*3+a1)<<20
__global__ void fill_csr_kernel(const int* __restrict__ ei, const int* __restrict__ ea,
                                int* __restrict__ cursor, int* __restrict__ epack, int E) {
  int e = blockIdx.x * 256 + threadIdx.x;
  if (e >= E) return;
  int slot = atomicAdd(&cursor[ei[E + e]], 1);
  int a = ea[2 * e] * 3 + ea[2 * e + 1];
  epack[slot] = (ei[e] & 0xFFFFF) | (a << 20);
}

// ---------------- weight convert+transpose+pad to bf16 ----------------
__global__ void convert_w1_kernel(const float* __restrict__ w1, bf16_t* __restrict__ o) {
  int id = blockIdx.x * 256 + threadIdx.x;
  if (id >= 5 * 640 * 320) return;
  int k = id % 320;
  int n = (id / 320) % 640;
  int l = id / (320 * 640);
  float v = (k < 300 && n < 600) ? w1[(size_t)l * 300 * 600 + (size_t)k * 600 + n] : 0.f;
  o[id] = (bf16_t)v;
}

__global__ void convert_w2_kernel(const float* __restrict__ w2, bf16_t* __restrict__ o) {
  int id = blockIdx.x * 256 + threadIdx.x;
  if (id >= 5 * 384 * 640) return;
  int k = id % 640;
  int n = (id / 640) % 384;
  int l = id / (640 * 384);
  float v = (k < 600 && n < 300) ? w2[(size_t)l * 600 * 300 + (size_t)k * 300 + n] : 0.f;
  o[id] = (bf16_t)v;
}

// combined edge table: T12[l][a0*3+a1][col] = ee1[l][a0][col] + ee2[l][a1][col]
__global__ void build_t12_kernel(const float* __restrict__ ee1, const float* __restrict__ ee2,
                                 bf16_t* __restrict__ T12) {
  int id = blockIdx.x * 256 + threadIdx.x;
  if (id >= 5 * 21 * 320) return;
  int col = id % 320;
  int r = id / 320;
  int l = r / 21;
  int a = r % 21;
  int a0 = a / 3, a1 = a % 3;
  float v = 0.f;
  if (col < 300) v = ee1[((size_t)l * 7 + a0) * 300 + col] + ee2[((size_t)l * 3 + a1) * 300 + col];
  T12[id] = (bf16_t)v;
}

// ---------------- aggregation: wave per node, CSR gather, bf16x8 ----------------
__global__ void aggregate_kernel(const bf16_t* __restrict__ h, const int* __restrict__ rowptr,
                                 const int* __restrict__ epack, const bf16_t* __restrict__ T12L,
                                 bf16_t* __restrict__ agg, int N) {
  const int w = (blockIdx.x * blockDim.x + threadIdx.x) >> 6;
  const int lane = threadIdx.x & 63;
  if (w >= N || lane >= 40) return;
  const int co = lane * 8;
  const int beg = rowptr[w], end = rowptr[w + 1];
  float acc[8];
  {
    bf16x8 hv = *(const bf16x8*)&h[(size_t)w * 320 + co];
    bf16x8 tv = *(const bf16x8*)&T12L[12 * 320 + co];  // self loop: a0=4,a1=0
    #pragma unroll
    for (int j = 0; j < 8; j++) acc[j] = (float)hv[j] + (float)tv[j];
  }
  for (int e = beg; e < end; e++) {
    const int p = epack[e];
    const int s = p & 0xFFFFF;
    const int a = (p >> 20) & 0x1F;
    bf16x8 hv = *(const bf16x8*)&h[(size_t)s * 320 + co];
    bf16x8 tv = *(const bf16x8*)&T12L[a * 320 + co];
    #pragma unroll
    for (int j = 0; j < 8; j++) acc[j] += (float)hv[j] + (float)tv[j];
  }
  bf16x8 o;
  #pragma unroll
  for (int j = 0; j < 8; j++) o[j] = (bf16_t)acc[j];
  *(bf16x8*)&agg[(size_t)w * 320 + co] = o;
}

// ---------------- MFMA GEMM: 128x128 tile, BK=32, dbuf in 32 KB, XOR-swizzled ----
// Pipeline: per phase, stage the OTHER buffer (4 x global_load_lds) BEFORE the
// 16 MFMA on the current buffer; __syncthreads' vmcnt(0) then drains loads that
// had a full compute phase in flight. Static distinct arrays (As0/As1) keep the
// LDS footprint at 32 KB (3 blocks/CU, register-capped) and keep alias analysis
// from fencing buffer-0 reads behind buffer-1 loads.
// LDS as 16B slots: slot(row,chunk4) = row*4 + (chunk ^ (row&3)); fragment read
// ck = quad ^ (ml&3) -> 64 lanes cover a contiguous permuted 1 KB = conflict-free.
// Grid: 1-D, y-fastest (blocks sharing an A-panel are consecutive) + bijective
// XCD chunk swizzle (m204) so they land on the same XCD's L2.
// STATS: fused BN column stats (sum, sumsq over rows < Nvalid) from f32 acc.
template <int LDA, int LDB, int LDC, int NK, int GY, int NBIAS, bool RELU, bool STATS>
__global__ __launch_bounds__(256) void gemm_kernel(const bf16_t* __restrict__ A,
                                                   const bf16_t* __restrict__ BT,
                                                   const float* __restrict__ bias,
                                                   bf16_t* __restrict__ C,
                                                   float* __restrict__ sums,
                                                   float* __restrict__ sumsq,
                                                   int Nvalid, int nwg) {
  __shared__ __align__(16) bf16_t As0[128 * 32];  // 8 KB each, 32 KB total
  __shared__ __align__(16) bf16_t Bs0[128 * 32];
  __shared__ __align__(16) bf16_t As1[128 * 32];
  __shared__ __align__(16) bf16_t Bs1[128 * 32];

  const int tid = threadIdx.x;
  const int lane = tid & 63;
  const int wave = tid >> 6;
  const int ml = lane & 15, quad = lane >> 4;
  const int wm = (wave & 1) * 64, wn = (wave >> 1) * 64;
  const int kx = ml & 3;  // fragment-read swizzle key

  // bijective XCD swizzle: hw xcd = bid%8; give each XCD a contiguous logical span
  const int bid = blockIdx.x;
  const int q = nwg >> 3, r = nwg & 7;
  const int xcd = bid & 7, pos = bid >> 3;
  const int logical = (xcd < r ? xcd * (q + 1) : r * (q + 1) + (xcd - r) * q) + pos;
  const size_t bm = (size_t)(logical / GY) * 128;
  const size_t bnn = (size_t)(logical % GY) * 128;

  // staging: thread t, iter it -> slot = it*256+t; row = it*64 + (t>>2),
  // lds chunk = t&3, global chunk = (t&3) ^ (row&3)
  const int srow = tid >> 2;
  const int cg = (tid & 3) ^ (srow & 3);
  const bf16_t* ag = A + (bm + srow) * LDA + cg * 8;
  const bf16_t* bg = BT + (bnn + srow) * LDB + cg * 8;

  auto stage = [&](bf16_t* as, bf16_t* bs, int kb) {
    const int kof = kb * 32;
    #pragma unroll
    for (int it = 0; it < 2; it++) {
      g2l16(ag + (size_t)it * 64 * LDA + kof, (void*)&as[((size_t)it * 256 + tid) * 8]);
      g2l16(bg + (size_t)it * 64 * LDB + kof, (void*)&bs[((size_t)it * 256 + tid) * 8]);
    }
  };

  f32x4 acc[4][4];
  #pragma unroll
  for (int rr = 0; rr < 4; rr++)
    #pragma unroll
    for (int cc = 0; cc < 4; cc++) acc[rr][cc] = (f32x4){0.f, 0.f, 0.f, 0.f};

  auto compute = [&](const bf16_t* as, const bf16_t* bs) {
    const int ck = quad ^ kx;
    bf16x8 aF[4], bF[4];
    #pragma unroll
    for (int mf = 0; mf < 4; mf++)
      aF[mf] = *(const bf16x8*)&as[((wm + mf * 16 + ml) * 4 + ck) * 8];
    #pragma unroll
    for (int nf = 0; nf < 4; nf++)
      bF[nf] = *(const bf16x8*)&bs[((wn + nf * 16 + ml) * 4 + ck) * 8];
    #pragma unroll
    for (int mf = 0; mf < 4; mf++)
      #pragma unroll
      for (int nf = 0; nf < 4; nf++)
        acc[mf][nf] = __builtin_amdgcn_mfma_f32_16x16x32_bf16(aF[mf], bF[nf], acc[mf][nf], 0, 0, 0);
  };

  stage(As0, Bs0, 0);
  __syncthreads();  // tile 0 resident

  #pragma unroll 2
  for (int kp = 0; kp < NK / 2; kp++) {  // NK even (10 or 20)
    stage(As1, Bs1, 2 * kp + 1);     // prefetch issues BEFORE compute
    compute(As0, Bs0);
    __syncthreads();                 // drains vmcnt: tile 2kp+1 resident; As0 free
    if (kp + 1 < NK / 2) stage(As0, Bs0, 2 * kp + 2);
    compute(As1, Bs1);
    __syncthreads();                 // drains vmcnt: tile 2kp+2 resident; As1 free
  }

  // epilogue: C/D layout col=lane&15, row=quad*4+reg
  #pragma unroll
  for (int nf = 0; nf < 4; nf++) {
    const int colg = (int)bnn + wn + nf * 16 + ml;
    const float bv = (colg < NBIAS) ? bias[colg] : 0.f;
    float s = 0.f, sq = 0.f;
    #pragma unroll
    for (int mf = 0; mf < 4; mf++) {
      #pragma unroll
      for (int i = 0; i < 4; i++) {
        const size_t rowg = bm + wm + mf * 16 + quad * 4 + i;
        float v = acc[mf][nf][i] + bv;
        if (RELU) v = fmaxf(v, 0.f);
        C[rowg * LDC + colg] = (bf16_t)v;
        if (STATS) {
          const bool ok = rowg < (size_t)Nvalid;
          s += ok ? v : 0.f;
          sq += ok ? v * v : 0.f;
        }
      }
    }
    if (STATS) {
      // reduce across quads (lanes ml, ml+16, ml+32, ml+48 share colg)
      s += __shfl_down(s, 16);
      sq += __shfl_down(sq, 16);
      s += __shfl_down(s, 32);
      sq += __shfl_down(sq, 32);
      if (quad == 0) {
        atomicAdd(&sums[colg], s);
        atomicAdd(&sumsq[colg], sq);
      }
    }
  }
}

// ---------------- BN ----------------
__global__ void bn_params_kernel(const float* __restrict__ sums, const float* __restrict__ sumsq,
                                 const float* __restrict__ gamma, const float* __restrict__ beta,
                                 float* __restrict__ scale, float* __restrict__ shift, int N) {
  const int col = threadIdx.x;
  if (col >= 384) return;
  if (col >= 300) {  // pad cols: force h pad to 0
    scale[col] = 0.f;
    shift[col] = 0.f;
    return;
  }
  const float inv = 1.f / (float)N;
  const float mean = sums[col] * inv;
  float var = sumsq[col] * inv - mean * mean;
  if (var < 0.f) var = 0.f;
  const float sc = gamma[col] * rsqrtf(var + 1e-5f);
  scale[col] = sc;
  shift[col] = beta[col] - mean * sc;
}

// wave per node, lane<40 handles 8 cols
__global__ void bn_apply_kernel(const bf16_t* __restrict__ H2, const float* __restrict__ scale,
                                const float* __restrict__ shift, bf16_t* __restrict__ h,
                                float* __restrict__ out, int relu, int last, int N) {
  const int w = (blockIdx.x * blockDim.x + threadIdx.x) >> 6;
  const int lane = threadIdx.x & 63;
  if (w >= N || lane >= 40) return;
  const int co = lane * 8;
  bf16x8 v8 = *(const bf16x8*)&H2[(size_t)w * 384 + co];
  f32x4 s0 = *(const f32x4*)&scale[co];
  f32x4 s1 = *(const f32x4*)&scale[co + 4];
  f32x4 t0 = *(const f32x4*)&shift[co];
  f32x4 t1 = *(const f32x4*)&shift[co + 4];
  float vv[8];
  #pragma unroll
  for (int j = 0; j < 8; j++) {
    float sc = (j < 4) ? s0[j] : s1[j - 4];
    float sh = (j < 4) ? t0[j] : t1[j - 4];
    float v = (float)v8[j] * sc + sh;
    if (relu) v = fmaxf(v, 0.f);
    vv[j] = v;
  }
  if (!last) {
    bf16x8 o;
    #pragma unroll
    for (int j = 0; j < 8; j++) o[j] = (bf16_t)vv[j];
    *(bf16x8*)&h[(size_t)w * 320 + co] = o;
  } else {
    #pragma unroll
    for (int j = 0; j < 8; j++)
      if (co + j < 300) out[(size_t)w * 300 + co + j] = vv[j];
  }
}

// ---------------- launch ----------------
extern "C" void kernel_launch(void* const* d_in, const int* in_sizes, int n_in,
                              void* d_out, int out_size, void* d_ws, size_t ws_size,
                              hipStream_t stream) {
  const int* x = (const int*)d_in[0];
  const int* ei = (const int*)d_in[1];
  const int* ea = (const int*)d_in[2];
  const float* xe1 = (const float*)d_in[3];
  const float* xe2 = (const float*)d_in[4];
  const float* ee1 = (const float*)d_in[5];
  const float* ee2 = (const float*)d_in[6];
  const float* w1 = (const float*)d_in[7];
  const float* b1 = (const float*)d_in[8];
  const float* w2 = (const float*)d_in[9];
  const float* b2 = (const float*)d_in[10];
  const float* gam = (const float*)d_in[11];
  const float* bet = (const float*)d_in[12];

  const int N = in_sizes[0] / 2;   // 100000
  const int E = in_sizes[1] / 2;   // 200000
  const int Mt = (N + 127) / 128;  // 782
  const size_t Mp = (size_t)Mt * 128;

  char* p = (char*)d_ws;
  auto take = [&](size_t b) -> char* {
    char* r = p;
    p += (b + 255) & ~(size_t)255;
    return r;
  };
  bf16_t* h    = (bf16_t*)take(Mp * 320 * 2);
  bf16_t* agg  = (bf16_t*)take(Mp * 320 * 2);
  bf16_t* C1   = (bf16_t*)take(Mp * 640 * 2);
  bf16_t* H2   = (bf16_t*)take(Mp * 384 * 2);
  bf16_t* W1bT = (bf16_t*)take((size_t)5 * 640 * 320 * 2);
  bf16_t* W2bT = (bf16_t*)take((size_t)5 * 384 * 640 * 2);
  bf16_t* T12  = (bf16_t*)take((size_t)5 * 21 * 320 * 2);
  int* deg     = (int*)take((size_t)N * 4);
  int* rowptr  = (int*)take((size_t)(N + 1) * 4);
  int* cursor  = (int*)take((size_t)N * 4);
  int* part    = (int*)take(1024 * 4);
  int* epack   = (int*)take((size_t)E * 4);
  float* sums  = (float*)take(384 * 4);
  float* sumsq = (float*)take(384 * 4);
  float* scale = (float*)take(384 * 4);
  float* shift = (float*)take(384 * 4);

  // agg pad rows must be exact zeros for GEMM1 (aggregate writes rows<N only)
  hipMemsetAsync(agg, 0, Mp * 320 * 2, stream);
  hipMemsetAsync(deg, 0, (size_t)N * 4, stream);

  const int nwb = (N + 3) / 4;  // wave-per-node, 4 waves per 256-thread block
  embed_kernel<<<nwb, 256, 0, stream>>>(x, xe1, xe2, h, N);

  count_deg_kernel<<<(E + 255) / 256, 256, 0, stream>>>(ei, deg, E);
  const int nsb = (N + 255) / 256;  // 391 (<=1024 for scan_block)
  scan_partial_kernel<<<nsb, 256, 0, stream>>>(deg, part, N);
  scan_block_kernel<<<1, 1024, 0, stream>>>(part, nsb);
  scan_final_kernel<<<nsb, 256, 0, stream>>>(deg, part, rowptr, cursor, N, E);
  fill_csr_kernel<<<(E + 255) / 256, 256, 0, stream>>>(ei, ea, cursor, epack, E);

  convert_w1_kernel<<<(5 * 640 * 320 + 255) / 256, 256, 0, stream>>>(w1, W1bT);
  convert_w2_kernel<<<(5 * 384 * 640 + 255) / 256, 256, 0, stream>>>(w2, W2bT);
  build_t12_kernel<<<(5 * 21 * 320 + 255) / 256, 256, 0, stream>>>(ee1, ee2, T12);

  const int nwg1 = Mt * 5;  // 3910
  const int nwg2 = Mt * 3;  // 2346

  for (int l = 0; l < 5; l++) {
    aggregate_kernel<<<nwb, 256, 0, stream>>>(h, rowptr, epack, T12 + (size_t)l * 21 * 320,
                                              agg, N);
    // GEMM1: [Mp,320] x W1T[640,320] -> C1[Mp,640], bias b1 (600), ReLU
    gemm_kernel<320, 320, 640, 10, 5, 600, true, false>
        <<<nwg1, 256, 0, stream>>>(agg, W1bT + (size_t)l * 640 * 320,
                                   b1 + (size_t)l * 600, C1, sums, sumsq, N, nwg1);
    // zero stats before GEMM2's fused bn_stats epilogue
    hipMemsetAsync(sums, 0, 384 * 4, stream);
    hipMemsetAsync(sumsq, 0, 384 * 4, stream);
    // GEMM2: [Mp,640] x W2T[384,640] -> H2[Mp,384], bias b2 (300), fused col stats
    gemm_kernel<640, 640, 384, 20, 3, 300, false, true>
        <<<nwg2, 256, 0, stream>>>(C1, W2bT + (size_t)l * 384 * 640,
                                   b2 + (size_t)l * 300, H2, sums, sumsq, N, nwg2);
    bn_params_kernel<<<1, 384, 0, stream>>>(sums, sumsq, gam + (size_t)l * 300,
                                            bet + (size_t)l * 300, scale, shift, N);
    bn_apply_kernel<<<nwb, 256, 0, stream>>>(H2, scale, shift, h, (float*)d_out,
                                             (l < 4) ? 1 : 0, (l == 4) ? 1 : 0, N);
  }
}

// Round 3
// 1367.242 us; speedup vs baseline: 1.3328x; 1.1855x over previous
//
#include <hip/hip_runtime.h>
#include <hip/hip_bf16.h>
#include <stdint.h>

typedef __bf16 bf16_t;
typedef bf16_t bf16x8 __attribute__((ext_vector_type(8)));
typedef float  f32x4  __attribute__((ext_vector_type(4)));

// ---------------- async global->LDS (16B per lane) ----------------
__device__ __forceinline__ void g2l16(const void* gp, void* lp) {
  __builtin_amdgcn_global_load_lds(
      (const __attribute__((address_space(1))) unsigned int*)(uintptr_t)gp,
      (__attribute__((address_space(3))) unsigned int*)(uint32_t)(uintptr_t)lp,
      16, 0, 0);
}

// ---------------- embed: h[i] = x_emb1[x[i,0]] + x_emb2[x[i,1]] ----------------
__global__ void embed_kernel(const int* __restrict__ x, const float* __restrict__ e1,
                             const float* __restrict__ e2, bf16_t* __restrict__ h, int N) {
  const int w = (blockIdx.x * blockDim.x + threadIdx.x) >> 6;
  const int lane = threadIdx.x & 63;
  if (w >= N || lane >= 40) return;
  const int t0 = x[2 * w], t1 = x[2 * w + 1];
  const int co = lane * 8;
  f32x4 a0 = *(const f32x4*)&e1[t0 * 300 + co];
  f32x4 a1 = *(const f32x4*)&e1[t0 * 300 + co + 4];
  f32x4 b0 = *(const f32x4*)&e2[t1 * 300 + co];
  f32x4 b1 = *(const f32x4*)&e2[t1 * 300 + co + 4];
  bf16x8 o;
  #pragma unroll
  for (int j = 0; j < 8; j++) {
    float v = (j < 4) ? (a0[j] + b0[j]) : (a1[j - 4] + b1[j - 4]);
    o[j] = (co + j < 300) ? (bf16_t)v : (bf16_t)0.f;
  }
  *(bf16x8*)&h[(size_t)w * 320 + co] = o;
}

// ---------------- CSR build ----------------
__global__ void count_deg_kernel(const int* __restrict__ ei, int* __restrict__ deg, int E) {
  int e = blockIdx.x * 256 + threadIdx.x;
  if (e < E) atomicAdd(&deg[ei[E + e]], 1);
}

__global__ void scan_partial_kernel(const int* __restrict__ deg, int* __restrict__ part, int N) {
  __shared__ int s[256];
  const int tid = threadIdx.x;
  const int idx = blockIdx.x * 256 + tid;
  s[tid] = (idx < N) ? deg[idx] : 0;
  __syncthreads();
  for (int off = 128; off > 0; off >>= 1) {
    if (tid < off) s[tid] += s[tid + off];
    __syncthreads();
  }
  if (tid == 0) part[blockIdx.x] = s[0];
}

__global__ void scan_block_kernel(int* __restrict__ part, int n) {  // n <= 1024
  __shared__ int s[1024];
  const int tid = threadIdx.x;
  const int v = (tid < n) ? part[tid] : 0;
  s[tid] = v;
  __syncthreads();
  for (int off = 1; off < 1024; off <<= 1) {
    int x = (tid >= off) ? s[tid - off] : 0;
    __syncthreads();
    s[tid] += x;
    __syncthreads();
  }
  if (tid < n) part[tid] = s[tid] - v;  // exclusive
}

__global__ void scan_final_kernel(const int* __restrict__ deg, const int* __restrict__ part,
                                  int* __restrict__ rowptr, int* __restrict__ cursor, int N, int E) {
  __shared__ int s[256];
  const int tid = threadIdx.x;
  const int idx = blockIdx.x * 256 + tid;
  const int v = (idx < N) ? deg[idx] : 0;
  s[tid] = v;
  __syncthreads();
  for (int off = 1; off < 256; off <<= 1) {
    int x = (tid >= off) ? s[tid - off] : 0;
    __syncthreads();
    s[tid] += x;
    __syncthreads();
  }
  if (idx < N) {
    int ex = s[tid] - v + part[blockIdx.x];
    rowptr[idx] = ex;
    cursor[idx] = ex;
  }
  if (idx == 0) rowptr[N] = E;
}

// pack src | (a0*3+a1)<<20
__global__ void fill_csr_kernel(const int* __restrict__ ei, const int* __restrict__ ea,
                                int* __restrict__ cursor, int* __restrict__ epack, int E) {
  int e = blockIdx.x * 256 + threadIdx.x;
  if (e >= E) return;
  int slot = atomicAdd(&cursor[ei[E + e]], 1);
  int a = ea[2 * e] * 3 + ea[2 * e + 1];
  epack[slot] = (ei[e] & 0xFFFFF) | (a << 20);
}

// ---------------- weight convert+transpose+pad to bf16 ----------------
__global__ void convert_w1_kernel(const float* __restrict__ w1, bf16_t* __restrict__ o) {
  int id = blockIdx.x * 256 + threadIdx.x;
  if (id >= 5 * 640 * 320) return;
  int k = id % 320;
  int n = (id / 320) % 640;
  int l = id / (320 * 640);
  float v = (k < 300 && n < 600) ? w1[(size_t)l * 300 * 600 + (size_t)k * 600 + n] : 0.f;
  o[id] = (bf16_t)v;
}

__global__ void convert_w2_kernel(const float* __restrict__ w2, bf16_t* __restrict__ o) {
  int id = blockIdx.x * 256 + threadIdx.x;
  if (id >= 5 * 384 * 640) return;
  int k = id % 640;
  int n = (id / 640) % 384;
  int l = id / (640 * 384);
  float v = (k < 600 && n < 300) ? w2[(size_t)l * 600 * 300 + (size_t)k * 300 + n] : 0.f;
  o[id] = (bf16_t)v;
}

// combined edge table: T12[l][a0*3+a1][col] = ee1[l][a0][col] + ee2[l][a1][col]
__global__ void build_t12_kernel(const float* __restrict__ ee1, const float* __restrict__ ee2,
                                 bf16_t* __restrict__ T12) {
  int id = blockIdx.x * 256 + threadIdx.x;
  if (id >= 5 * 21 * 320) return;
  int col = id % 320;
  int r = id / 320;
  int l = r / 21;
  int a = r % 21;
  int a0 = a / 3, a1 = a % 3;
  float v = 0.f;
  if (col < 300) v = ee1[((size_t)l * 7 + a0) * 300 + col] + ee2[((size_t)l * 3 + a1) * 300 + col];
  T12[id] = (bf16_t)v;
}

// ---------------- aggregation: thread-centric (node = g/40), fused BN ----------
// FUSE_BN: source rows are H2 (LDH=384) pre-BN; apply v*scale+shift then relu on
// the fly (replaces the separate bn_apply pass for layers 1..4).
template <bool FUSE_BN>
__global__ void aggregate_kernel(const bf16_t* __restrict__ hsrc, const int* __restrict__ rowptr,
                                 const int* __restrict__ epack, const bf16_t* __restrict__ T12L,
                                 const float* __restrict__ scale, const float* __restrict__ shift,
                                 bf16_t* __restrict__ agg, int N, int LDH) {
  const int g = blockIdx.x * 256 + threadIdx.x;
  const int w = g / 40;
  if (w >= N) return;
  const int co = (g - w * 40) * 8;

  float sc[8], sh[8];
  if (FUSE_BN) {
    f32x4 s0 = *(const f32x4*)&scale[co];
    f32x4 s1 = *(const f32x4*)&scale[co + 4];
    f32x4 t0 = *(const f32x4*)&shift[co];
    f32x4 t1 = *(const f32x4*)&shift[co + 4];
    #pragma unroll
    for (int j = 0; j < 4; j++) { sc[j] = s0[j]; sc[j + 4] = s1[j]; sh[j] = t0[j]; sh[j + 4] = t1[j]; }
  }

  const int beg = rowptr[w], end = rowptr[w + 1];
  float acc[8];
  {
    bf16x8 hv = *(const bf16x8*)&hsrc[(size_t)w * LDH + co];
    bf16x8 tv = *(const bf16x8*)&T12L[12 * 320 + co];  // self loop: a0=4,a1=0
    #pragma unroll
    for (int j = 0; j < 8; j++) {
      float v = (float)hv[j];
      if (FUSE_BN) v = fmaxf(v * sc[j] + sh[j], 0.f);
      acc[j] = v + (float)tv[j];
    }
  }
  for (int e = beg; e < end; e++) {
    const int p = epack[e];
    const int s = p & 0xFFFFF;
    const int a = (p >> 20) & 0x1F;
    bf16x8 hv = *(const bf16x8*)&hsrc[(size_t)s * LDH + co];
    bf16x8 tv = *(const bf16x8*)&T12L[a * 320 + co];
    #pragma unroll
    for (int j = 0; j < 8; j++) {
      float v = (float)hv[j];
      if (FUSE_BN) v = fmaxf(v * sc[j] + sh[j], 0.f);
      acc[j] += v + (float)tv[j];
    }
  }
  bf16x8 o;
  #pragma unroll
  for (int j = 0; j < 8; j++) o[j] = (bf16_t)acc[j];
  *(bf16x8*)&agg[(size_t)w * 320 + co] = o;
}

// ---------------- MFMA GEMM: 128x128 tile, BK=32, 3-buffer ring, counted vmcnt ---
// T3+T4 port (m201 pattern): ring of 3 LDS buffers (48 KB = 3 blocks/CU, matching
// the register cap). Per K-step: issue stage(k+2) -> s_waitcnt vmcnt(8) (tiles
// k+1,k+2 = 8 g2l16 stay in flight; tile k's 4 are drained) -> s_barrier ->
// compute(k) -> s_barrier (protects buffer k%3 from stage(k+3)). Loads get ~2
// compute phases (~1600cy) to cover ~900cy HBM latency.
// Swizzle fix (r2 had 6M conflicts): key = (ml>>1)&3, NOT ml&3. Bank group of a
// fragment read = 16*(row&1) + 4*ck; with ck = quad^((ml>>1)&3) the 16 lanes of
// an LDS phase cover all 8 groups, 2 lanes each = free (m136).
// Grid: 1-D y-fastest + bijective XCD chunk swizzle (keeps r2's FETCH win).
// STATS: fused BN column stats (sum, sumsq over rows < Nvalid) from f32 acc.
template <int LDA, int LDB, int LDC, int NK, int GY, int NBIAS, bool RELU, bool STATS>
__global__ __launch_bounds__(256) void gemm_kernel(const bf16_t* __restrict__ A,
                                                   const bf16_t* __restrict__ BT,
                                                   const float* __restrict__ bias,
                                                   bf16_t* __restrict__ C,
                                                   float* __restrict__ sums,
                                                   float* __restrict__ sumsq,
                                                   int Nvalid, int nwg) {
  __shared__ __align__(16) bf16_t As0[128 * 32];  // 8 KB each, 48 KB total
  __shared__ __align__(16) bf16_t Bs0[128 * 32];
  __shared__ __align__(16) bf16_t As1[128 * 32];
  __shared__ __align__(16) bf16_t Bs1[128 * 32];
  __shared__ __align__(16) bf16_t As2[128 * 32];
  __shared__ __align__(16) bf16_t Bs2[128 * 32];

  const int tid = threadIdx.x;
  const int lane = tid & 63;
  const int wave = tid >> 6;
  const int ml = lane & 15, quad = lane >> 4;
  const int wm = (wave & 1) * 64, wn = (wave >> 1) * 64;
  const int kx = (ml >> 1) & 3;  // fragment-read swizzle key (row bits 1..2)

  // bijective XCD swizzle: hw xcd = bid%8; each XCD gets a contiguous logical span
  const int bid = blockIdx.x;
  const int q = nwg >> 3, r = nwg & 7;
  const int xcd = bid & 7, pos = bid >> 3;
  const int logical = (xcd < r ? xcd * (q + 1) : r * (q + 1) + (xcd - r) * q) + pos;
  const size_t bm = (size_t)(logical / GY) * 128;
  const size_t bnn = (size_t)(logical % GY) * 128;

  // staging: thread t, iter it -> slot = it*256+t; row = it*64 + (t>>2),
  // lds chunk = t&3, global chunk = (t&3) ^ ((row>>1)&3) = (t&3) ^ ((t>>3)&3)
  const int srow = tid >> 2;
  const int cg = (tid & 3) ^ ((tid >> 3) & 3);
  const bf16_t* ag = A + (bm + srow) * LDA + cg * 8;
  const bf16_t* bg = BT + (bnn + srow) * LDB + cg * 8;

  auto stage = [&](bf16_t* as, bf16_t* bs, int kb) {
    const int kof = kb * 32;
    #pragma unroll
    for (int it = 0; it < 2; it++) {
      g2l16(ag + (size_t)it * 64 * LDA + kof, (void*)&as[((size_t)it * 256 + tid) * 8]);
      g2l16(bg + (size_t)it * 64 * LDB + kof, (void*)&bs[((size_t)it * 256 + tid) * 8]);
    }
  };
  auto bufA = [&](int i) -> bf16_t* { return i == 0 ? As0 : (i == 1 ? As1 : As2); };
  auto bufB = [&](int i) -> bf16_t* { return i == 0 ? Bs0 : (i == 1 ? Bs1 : Bs2); };

  f32x4 acc[4][4];
  #pragma unroll
  for (int rr = 0; rr < 4; rr++)
    #pragma unroll
    for (int cc = 0; cc < 4; cc++) acc[rr][cc] = (f32x4){0.f, 0.f, 0.f, 0.f};

  auto compute = [&](const bf16_t* as, const bf16_t* bs) {
    const int ck = quad ^ kx;
    bf16x8 aF[4], bF[4];
    #pragma unroll
    for (int mf = 0; mf < 4; mf++)
      aF[mf] = *(const bf16x8*)&as[((wm + mf * 16 + ml) * 4 + ck) * 8];
    #pragma unroll
    for (int nf = 0; nf < 4; nf++)
      bF[nf] = *(const bf16x8*)&bs[((wn + nf * 16 + ml) * 4 + ck) * 8];
    #pragma unroll
    for (int mf = 0; mf < 4; mf++)
      #pragma unroll
      for (int nf = 0; nf < 4; nf++)
        acc[mf][nf] = __builtin_amdgcn_mfma_f32_16x16x32_bf16(aF[mf], bF[nf], acc[mf][nf], 0, 0, 0);
  };

  stage(As0, Bs0, 0);
  stage(As1, Bs1, 1);  // 8 g2l16 in flight

  #pragma unroll
  for (int kb = 0; kb < NK; kb++) {
    if (kb + 2 < NK) {
      stage(bufA((kb + 2) % 3), bufB((kb + 2) % 3), kb + 2);
      asm volatile("s_waitcnt vmcnt(8)" ::: "memory");  // tile kb done; kb+1,kb+2 in flight
    } else if (kb + 1 < NK) {
      asm volatile("s_waitcnt vmcnt(4)" ::: "memory");
    } else {
      asm volatile("s_waitcnt vmcnt(0)" ::: "memory");
    }
    __builtin_amdgcn_s_barrier();        // all waves' tile-kb writes landed
    __builtin_amdgcn_sched_barrier(0);   // rule #18: pin ds_reads after barrier
    compute(bufA(kb % 3), bufB(kb % 3));
    __builtin_amdgcn_sched_barrier(0);
    __builtin_amdgcn_s_barrier();        // buffer kb%3 free for stage(kb+3)
  }

  // epilogue: C/D layout col=lane&15, row=quad*4+reg
  #pragma unroll
  for (int nf = 0; nf < 4; nf++) {
    const int colg = (int)bnn + wn + nf * 16 + ml;
    const float bv = (colg < NBIAS) ? bias[colg] : 0.f;
    float s = 0.f, sq = 0.f;
    #pragma unroll
    for (int mf = 0; mf < 4; mf++) {
      #pragma unroll
      for (int i = 0; i < 4; i++) {
        const size_t rowg = bm + wm + mf * 16 + quad * 4 + i;
        float v = acc[mf][nf][i] + bv;
        if (RELU) v = fmaxf(v, 0.f);
        C[rowg * LDC + colg] = (bf16_t)v;
        if (STATS) {
          const bool ok = rowg < (size_t)Nvalid;
          s += ok ? v : 0.f;
          sq += ok ? v * v : 0.f;
        }
      }
    }
    if (STATS) {
      // reduce across quads (lanes ml, ml+16, ml+32, ml+48 share colg)
      s += __shfl_down(s, 16);
      sq += __shfl_down(sq, 16);
      s += __shfl_down(s, 32);
      sq += __shfl_down(sq, 32);
      if (quad == 0) {
        atomicAdd(&sums[colg], s);
        atomicAdd(&sumsq[colg], sq);
      }
    }
  }
}

// ---------------- BN ----------------
__global__ void bn_params_kernel(const float* __restrict__ sums, const float* __restrict__ sumsq,
                                 const float* __restrict__ gamma, const float* __restrict__ beta,
                                 float* __restrict__ scale, float* __restrict__ shift, int N) {
  const int col = threadIdx.x;
  if (col >= 384) return;
  if (col >= 300) {  // pad cols: force transformed pad to 0
    scale[col] = 0.f;
    shift[col] = 0.f;
    return;
  }
  const float inv = 1.f / (float)N;
  const float mean = sums[col] * inv;
  float var = sumsq[col] * inv - mean * mean;
  if (var < 0.f) var = 0.f;
  const float sc = gamma[col] * rsqrtf(var + 1e-5f);
  scale[col] = sc;
  shift[col] = beta[col] - mean * sc;
}

// final-layer output: wave per node, lane<40 handles 8 cols, writes f32 out
__global__ void bn_apply_kernel(const bf16_t* __restrict__ H2, const float* __restrict__ scale,
                                const float* __restrict__ shift, float* __restrict__ out, int N) {
  const int w = (blockIdx.x * blockDim.x + threadIdx.x) >> 6;
  const int lane = threadIdx.x & 63;
  if (w >= N || lane >= 40) return;
  const int co = lane * 8;
  bf16x8 v8 = *(const bf16x8*)&H2[(size_t)w * 384 + co];
  f32x4 s0 = *(const f32x4*)&scale[co];
  f32x4 s1 = *(const f32x4*)&scale[co + 4];
  f32x4 t0 = *(const f32x4*)&shift[co];
  f32x4 t1 = *(const f32x4*)&shift[co + 4];
  #pragma unroll
  for (int j = 0; j < 8; j++) {
    float sc = (j < 4) ? s0[j] : s1[j - 4];
    float sh = (j < 4) ? t0[j] : t1[j - 4];
    float v = (float)v8[j] * sc + sh;
    if (co + j < 300) out[(size_t)w * 300 + co + j] = v;
  }
}

// ---------------- launch ----------------
extern "C" void kernel_launch(void* const* d_in, const int* in_sizes, int n_in,
                              void* d_out, int out_size, void* d_ws, size_t ws_size,
                              hipStream_t stream) {
  const int* x = (const int*)d_in[0];
  const int* ei = (const int*)d_in[1];
  const int* ea = (const int*)d_in[2];
  const float* xe1 = (const float*)d_in[3];
  const float* xe2 = (const float*)d_in[4];
  const float* ee1 = (const float*)d_in[5];
  const float* ee2 = (const float*)d_in[6];
  const float* w1 = (const float*)d_in[7];
  const float* b1 = (const float*)d_in[8];
  const float* w2 = (const float*)d_in[9];
  const float* b2 = (const float*)d_in[10];
  const float* gam = (const float*)d_in[11];
  const float* bet = (const float*)d_in[12];

  const int N = in_sizes[0] / 2;   // 100000
  const int E = in_sizes[1] / 2;   // 200000
  const int Mt = (N + 127) / 128;  // 782
  const size_t Mp = (size_t)Mt * 128;

  char* p = (char*)d_ws;
  auto take = [&](size_t b) -> char* {
    char* r = p;
    p += (b + 255) & ~(size_t)255;
    return r;
  };
  bf16_t* h    = (bf16_t*)take(Mp * 320 * 2);
  bf16_t* agg  = (bf16_t*)take(Mp * 320 * 2);
  bf16_t* C1   = (bf16_t*)take(Mp * 640 * 2);
  bf16_t* H2   = (bf16_t*)take(Mp * 384 * 2);
  bf16_t* W1bT = (bf16_t*)take((size_t)5 * 640 * 320 * 2);
  bf16_t* W2bT = (bf16_t*)take((size_t)5 * 384 * 640 * 2);
  bf16_t* T12  = (bf16_t*)take((size_t)5 * 21 * 320 * 2);
  int* deg     = (int*)take((size_t)N * 4);
  int* rowptr  = (int*)take((size_t)(N + 1) * 4);
  int* cursor  = (int*)take((size_t)N * 4);
  int* part    = (int*)take(1024 * 4);
  int* epack   = (int*)take((size_t)E * 4);
  float* sums  = (float*)take(384 * 4);
  float* sumsq = (float*)take(384 * 4);
  float* scale = (float*)take(384 * 4);
  float* shift = (float*)take(384 * 4);

  // agg pad rows must be exact zeros for GEMM1 (aggregate writes rows<N only)
  hipMemsetAsync(agg, 0, Mp * 320 * 2, stream);
  hipMemsetAsync(deg, 0, (size_t)N * 4, stream);

  const int nwb = (N + 3) / 4;  // wave-per-node kernels
  embed_kernel<<<nwb, 256, 0, stream>>>(x, xe1, xe2, h, N);

  count_deg_kernel<<<(E + 255) / 256, 256, 0, stream>>>(ei, deg, E);
  const int nsb = (N + 255) / 256;  // 391 (<=1024 for scan_block)
  scan_partial_kernel<<<nsb, 256, 0, stream>>>(deg, part, N);
  scan_block_kernel<<<1, 1024, 0, stream>>>(part, nsb);
  scan_final_kernel<<<nsb, 256, 0, stream>>>(deg, part, rowptr, cursor, N, E);
  fill_csr_kernel<<<(E + 255) / 256, 256, 0, stream>>>(ei, ea, cursor, epack, E);

  convert_w1_kernel<<<(5 * 640 * 320 + 255) / 256, 256, 0, stream>>>(w1, W1bT);
  convert_w2_kernel<<<(5 * 384 * 640 + 255) / 256, 256, 0, stream>>>(w2, W2bT);
  build_t12_kernel<<<(5 * 21 * 320 + 255) / 256, 256, 0, stream>>>(ee1, ee2, T12);

  const int nwg1 = Mt * 5;  // 3910
  const int nwg2 = Mt * 3;  // 2346
  const int nab = (N * 40 + 255) / 256;  // thread-centric aggregate grid

  for (int l = 0; l < 5; l++) {
    if (l == 0) {
      aggregate_kernel<false><<<nab, 256, 0, stream>>>(h, rowptr, epack,
                                                       T12 + (size_t)l * 21 * 320,
                                                       scale, shift, agg, N, 320);
    } else {
      // reads H2 pre-BN; applies scale/shift (+relu) from previous layer's BN
      aggregate_kernel<true><<<nab, 256, 0, stream>>>(H2, rowptr, epack,
                                                      T12 + (size_t)l * 21 * 320,
                                                      scale, shift, agg, N, 384);
    }
    // GEMM1: [Mp,320] x W1T[640,320] -> C1[Mp,640], bias b1 (600), ReLU
    gemm_kernel<320, 320, 640, 10, 5, 600, true, false>
        <<<nwg1, 256, 0, stream>>>(agg, W1bT + (size_t)l * 640 * 320,
                                   b1 + (size_t)l * 600, C1, sums, sumsq, N, nwg1);
    // zero stats before GEMM2's fused bn_stats epilogue
    hipMemsetAsync(sums, 0, 384 * 4, stream);
    hipMemsetAsync(sumsq, 0, 384 * 4, stream);
    // GEMM2: [Mp,640] x W2T[384,640] -> H2[Mp,384], bias b2 (300), fused col stats
    gemm_kernel<640, 640, 384, 20, 3, 300, false, true>
        <<<nwg2, 256, 0, stream>>>(C1, W2bT + (size_t)l * 384 * 640,
                                   b2 + (size_t)l * 300, H2, sums, sumsq, N, nwg2);
    bn_params_kernel<<<1, 384, 0, stream>>>(sums, sumsq, gam + (size_t)l * 300,
                                            bet + (size_t)l * 300, scale, shift, N);
  }
  // final layer output: BN(H2) -> f32 out
  bn_apply_kernel<<<nwb, 256, 0, stream>>>(H2, scale, shift, (float*)d_out, N);
}

// Round 4
// 1366.771 us; speedup vs baseline: 1.3332x; 1.0003x over previous
//
#include <hip/hip_runtime.h>
#include <hip/hip_bf16.h>
#include <stdint.h>

typedef __bf16 bf16_t;
typedef bf16_t bf16x8 __attribute__((ext_vector_type(8)));
typedef float  f32x4  __attribute__((ext_vector_type(4)));

// ---------------- embed: h[i] = x_emb1[x[i,0]] + x_emb2[x[i,1]] ----------------
__global__ void embed_kernel(const int* __restrict__ x, const float* __restrict__ e1,
                             const float* __restrict__ e2, bf16_t* __restrict__ h, int N) {
  const int w = (blockIdx.x * blockDim.x + threadIdx.x) >> 6;
  const int lane = threadIdx.x & 63;
  if (w >= N || lane >= 40) return;
  const int t0 = x[2 * w], t1 = x[2 * w + 1];
  const int co = lane * 8;
  f32x4 a0 = *(const f32x4*)&e1[t0 * 300 + co];
  f32x4 a1 = *(const f32x4*)&e1[t0 * 300 + co + 4];
  f32x4 b0 = *(const f32x4*)&e2[t1 * 300 + co];
  f32x4 b1 = *(const f32x4*)&e2[t1 * 300 + co + 4];
  bf16x8 o;
  #pragma unroll
  for (int j = 0; j < 8; j++) {
    float v = (j < 4) ? (a0[j] + b0[j]) : (a1[j - 4] + b1[j - 4]);
    o[j] = (co + j < 300) ? (bf16_t)v : (bf16_t)0.f;
  }
  *(bf16x8*)&h[(size_t)w * 320 + co] = o;
}

// ---------------- CSR build ----------------
__global__ void count_deg_kernel(const int* __restrict__ ei, int* __restrict__ deg, int E) {
  int e = blockIdx.x * 256 + threadIdx.x;
  if (e < E) atomicAdd(&deg[ei[E + e]], 1);
}

__global__ void scan_partial_kernel(const int* __restrict__ deg, int* __restrict__ part, int N) {
  __shared__ int s[256];
  const int tid = threadIdx.x;
  const int idx = blockIdx.x * 256 + tid;
  s[tid] = (idx < N) ? deg[idx] : 0;
  __syncthreads();
  for (int off = 128; off > 0; off >>= 1) {
    if (tid < off) s[tid] += s[tid + off];
    __syncthreads();
  }
  if (tid == 0) part[blockIdx.x] = s[0];
}

__global__ void scan_block_kernel(int* __restrict__ part, int n) {  // n <= 1024
  __shared__ int s[1024];
  const int tid = threadIdx.x;
  const int v = (tid < n) ? part[tid] : 0;
  s[tid] = v;
  __syncthreads();
  for (int off = 1; off < 1024; off <<= 1) {
    int x = (tid >= off) ? s[tid - off] : 0;
    __syncthreads();
    s[tid] += x;
    __syncthreads();
  }
  if (tid < n) part[tid] = s[tid] - v;  // exclusive
}

__global__ void scan_final_kernel(const int* __restrict__ deg, const int* __restrict__ part,
                                  int* __restrict__ rowptr, int* __restrict__ cursor, int N, int E) {
  __shared__ int s[256];
  const int tid = threadIdx.x;
  const int idx = blockIdx.x * 256 + tid;
  const int v = (idx < N) ? deg[idx] : 0;
  s[tid] = v;
  __syncthreads();
  for (int off = 1; off < 256; off <<= 1) {
    int x = (tid >= off) ? s[tid - off] : 0;
    __syncthreads();
    s[tid] += x;
    __syncthreads();
  }
  if (idx < N) {
    int ex = s[tid] - v + part[blockIdx.x];
    rowptr[idx] = ex;
    cursor[idx] = ex;
  }
  if (idx == 0) rowptr[N] = E;
}

// pack src | (a0*3+a1)<<20
__global__ void fill_csr_kernel(const int* __restrict__ ei, const int* __restrict__ ea,
                                int* __restrict__ cursor, int* __restrict__ epack, int E) {
  int e = blockIdx.x * 256 + threadIdx.x;
  if (e >= E) return;
  int slot = atomicAdd(&cursor[ei[E + e]], 1);
  int a = ea[2 * e] * 3 + ea[2 * e + 1];
  epack[slot] = (ei[e] & 0xFFFFF) | (a << 20);
}

// ---------------- weight convert+transpose+pad to bf16 ----------------
__global__ void convert_w1_kernel(const float* __restrict__ w1, bf16_t* __restrict__ o) {
  int id = blockIdx.x * 256 + threadIdx.x;
  if (id >= 5 * 640 * 320) return;
  int k = id % 320;
  int n = (id / 320) % 640;
  int l = id / (320 * 640);
  float v = (k < 300 && n < 600) ? w1[(size_t)l * 300 * 600 + (size_t)k * 600 + n] : 0.f;
  o[id] = (bf16_t)v;
}

__global__ void convert_w2_kernel(const float* __restrict__ w2, bf16_t* __restrict__ o) {
  int id = blockIdx.x * 256 + threadIdx.x;
  if (id >= 5 * 384 * 640) return;
  int k = id % 640;
  int n = (id / 640) % 384;
  int l = id / (640 * 384);
  float v = (k < 600 && n < 300) ? w2[(size_t)l * 600 * 300 + (size_t)k * 300 + n] : 0.f;
  o[id] = (bf16_t)v;
}

// combined edge table: T12[l][a0*3+a1][col] = ee1[l][a0][col] + ee2[l][a1][col]
__global__ void build_t12_kernel(const float* __restrict__ ee1, const float* __restrict__ ee2,
                                 bf16_t* __restrict__ T12) {
  int id = blockIdx.x * 256 + threadIdx.x;
  if (id >= 5 * 21 * 320) return;
  int col = id % 320;
  int r = id / 320;
  int l = r / 21;
  int a = r % 21;
  int a0 = a / 3, a1 = a % 3;
  float v = 0.f;
  if (col < 300) v = ee1[((size_t)l * 7 + a0) * 300 + col] + ee2[((size_t)l * 3 + a1) * 300 + col];
  T12[id] = (bf16_t)v;
}

// ---------------- aggregation: thread-centric (node = g/40), fused BN ----------
template <bool FUSE_BN>
__global__ void aggregate_kernel(const bf16_t* __restrict__ hsrc, const int* __restrict__ rowptr,
                                 const int* __restrict__ epack, const bf16_t* __restrict__ T12L,
                                 const float* __restrict__ scale, const float* __restrict__ shift,
                                 bf16_t* __restrict__ agg, int N, int LDH) {
  const int g = blockIdx.x * 256 + threadIdx.x;
  const int w = g / 40;
  if (w >= N) return;
  const int co = (g - w * 40) * 8;

  float sc[8], sh[8];
  if (FUSE_BN) {
    f32x4 s0 = *(const f32x4*)&scale[co];
    f32x4 s1 = *(const f32x4*)&scale[co + 4];
    f32x4 t0 = *(const f32x4*)&shift[co];
    f32x4 t1 = *(const f32x4*)&shift[co + 4];
    #pragma unroll
    for (int j = 0; j < 4; j++) { sc[j] = s0[j]; sc[j + 4] = s1[j]; sh[j] = t0[j]; sh[j + 4] = t1[j]; }
  }

  const int beg = rowptr[w], end = rowptr[w + 1];
  float acc[8];
  {
    bf16x8 hv = *(const bf16x8*)&hsrc[(size_t)w * LDH + co];
    bf16x8 tv = *(const bf16x8*)&T12L[12 * 320 + co];  // self loop: a0=4,a1=0
    #pragma unroll
    for (int j = 0; j < 8; j++) {
      float v = (float)hv[j];
      if (FUSE_BN) v = fmaxf(v * sc[j] + sh[j], 0.f);
      acc[j] = v + (float)tv[j];
    }
  }
  for (int e = beg; e < end; e++) {
    const int p = epack[e];
    const int s = p & 0xFFFFF;
    const int a = (p >> 20) & 0x1F;
    bf16x8 hv = *(const bf16x8*)&hsrc[(size_t)s * LDH + co];
    bf16x8 tv = *(const bf16x8*)&T12L[a * 320 + co];
    #pragma unroll
    for (int j = 0; j < 8; j++) {
      float v = (float)hv[j];
      if (FUSE_BN) v = fmaxf(v * sc[j] + sh[j], 0.f);
      acc[j] += v + (float)tv[j];
    }
  }
  bf16x8 o;
  #pragma unroll
  for (int j = 0; j < 8; j++) o[j] = (bf16_t)acc[j];
  *(bf16x8*)&agg[(size_t)w * 320 + co] = o;
}

// ---------------- MFMA GEMM: 128x128 tile, BK=32, REGISTER-STAGED pipeline -------
// T14 form: global->VGPR loads issued EARLY (B depth-1 for L2-resident weights,
// A depth-2 for the HBM-streamed activations), ds_write LATE, one raw s_barrier +
// lgkmcnt(0) per K-step. No global_load_lds: the compiler's waitcnt machinery now
// tracks REGISTER deps precisely (ds_write of tile k+1 waits only its own loads,
// vmcnt counted automatically; ds_read->MFMA needs only lgkmcnt) -- removing the
// conservative vmcnt coupling that kept rounds 0-3 pinned at ~17% MfmaUtil.
// LDS 32 KB (2 buf x BK=32), 3 blocks/CU. Swizzle on BOTH ds_write and ds_read:
// LDS(row, c) holds global chunk c ^ ((row>>1)&3); read ck = quad ^ ((ml>>1)&3).
// Grid: 1-D y-fastest + bijective XCD chunk swizzle. STATS: fused BN col stats.
template <int LDA, int LDB, int LDC, int NK, int GY, int NBIAS, bool RELU, bool STATS>
__global__ __launch_bounds__(256, 3) void gemm_kernel(const bf16_t* __restrict__ A,
                                                      const bf16_t* __restrict__ BT,
                                                      const float* __restrict__ bias,
                                                      bf16_t* __restrict__ C,
                                                      float* __restrict__ sums,
                                                      float* __restrict__ sumsq,
                                                      int Nvalid, int nwg) {
  __shared__ __align__(16) bf16_t As0[128 * 32];  // 8 KB each, 32 KB total
  __shared__ __align__(16) bf16_t Bs0[128 * 32];
  __shared__ __align__(16) bf16_t As1[128 * 32];
  __shared__ __align__(16) bf16_t Bs1[128 * 32];

  const int tid = threadIdx.x;
  const int lane = tid & 63;
  const int wave = tid >> 6;
  const int ml = lane & 15, quad = lane >> 4;
  const int wm = (wave & 1) * 64, wn = (wave >> 1) * 64;
  const int kx = (ml >> 1) & 3;  // fragment-read swizzle key (row bits 1..2)

  // bijective XCD swizzle
  const int bid = blockIdx.x;
  const int q = nwg >> 3, r = nwg & 7;
  const int xcd = bid & 7, pos = bid >> 3;
  const int logical = (xcd < r ? xcd * (q + 1) : r * (q + 1) + (xcd - r) * q) + pos;
  const size_t bm = (size_t)(logical / GY) * 128;
  const size_t bnn = (size_t)(logical % GY) * 128;

  // staging map: thread t, half it in {0,1} -> row = it*64 + (t>>2),
  // lds slot = it*256 + t (chunk t&3), global chunk = (t&3) ^ ((t>>3)&3)
  const int srow = tid >> 2;
  const int cg = (tid & 3) ^ ((tid >> 3) & 3);
  const bf16_t* ag = A + (bm + srow) * LDA + cg * 8;
  const bf16_t* bg = BT + (bnn + srow) * LDB + cg * 8;

  auto loadA = [&](int kb, bf16x8& r0, bf16x8& r1) {
    const int kof = kb * 32;
    r0 = *(const bf16x8*)(ag + kof);
    r1 = *(const bf16x8*)(ag + (size_t)64 * LDA + kof);
  };
  auto loadB = [&](int kb, bf16x8& r0, bf16x8& r1) {
    const int kof = kb * 32;
    r0 = *(const bf16x8*)(bg + kof);
    r1 = *(const bf16x8*)(bg + (size_t)64 * LDB + kof);
  };
  auto store = [&](bf16_t* as, bf16_t* bs, const bf16x8& a0, const bf16x8& a1,
                   const bf16x8& b0, const bf16x8& b1) {
    *(bf16x8*)&as[(size_t)tid * 8] = a0;
    *(bf16x8*)&as[(256 + (size_t)tid) * 8] = a1;
    *(bf16x8*)&bs[(size_t)tid * 8] = b0;
    *(bf16x8*)&bs[(256 + (size_t)tid) * 8] = b1;
  };

  f32x4 acc[4][4];
  #pragma unroll
  for (int rr = 0; rr < 4; rr++)
    #pragma unroll
    for (int cc = 0; cc < 4; cc++) acc[rr][cc] = (f32x4){0.f, 0.f, 0.f, 0.f};

  auto compute = [&](const bf16_t* as, const bf16_t* bs) {
    const int ck = quad ^ kx;
    bf16x8 aF[4], bF[4];
    #pragma unroll
    for (int mf = 0; mf < 4; mf++)
      aF[mf] = *(const bf16x8*)&as[((wm + mf * 16 + ml) * 4 + ck) * 8];
    #pragma unroll
    for (int nf = 0; nf < 4; nf++)
      bF[nf] = *(const bf16x8*)&bs[((wn + nf * 16 + ml) * 4 + ck) * 8];
    #pragma unroll
    for (int mf = 0; mf < 4; mf++)
      #pragma unroll
      for (int nf = 0; nf < 4; nf++)
        acc[mf][nf] = __builtin_amdgcn_mfma_f32_16x16x32_bf16(aF[mf], bF[nf], acc[mf][nf], 0, 0, 0);
  };

  // prologue: A(0)->a[0], B(0)->b, A(1)->a[1]; stage tile 0 into buf0
  bf16x8 a[2][2], b[2];
  loadA(0, a[0][0], a[0][1]);
  loadB(0, b[0], b[1]);
  loadA(1, a[1][0], a[1][1]);
  store(As0, Bs0, a[0][0], a[0][1], b[0], b[1]);  // compiler waits vmcnt for A(0),B(0)
  asm volatile("s_waitcnt lgkmcnt(0)" ::: "memory");
  __builtin_amdgcn_s_barrier();
  __builtin_amdgcn_sched_barrier(0);

  #pragma unroll
  for (int kb = 0; kb < NK; kb++) {
    // issue loads early: B(k+1) first (needed this iter's store -> vmcnt counts
    // exclude the 2 A-loads issued after), then A(k+2) into the freed set.
    if (kb + 1 < NK) loadB(kb + 1, b[0], b[1]);
    if (kb + 2 < NK) loadA(kb + 2, a[kb % 2][0], a[kb % 2][1]);
    // compute on current buffer (pure LDS+MFMA, no vmem dependency)
    if ((kb & 1) == 0) compute(As0, Bs0); else compute(As1, Bs1);
    if (kb + 1 < NK) {
      // stage tile k+1: A from the set loaded 2 iters ago, B from this iter
      if ((kb & 1) == 0) store(As1, Bs1, a[(kb + 1) % 2][0], a[(kb + 1) % 2][1], b[0], b[1]);
      else               store(As0, Bs0, a[(kb + 1) % 2][0], a[(kb + 1) % 2][1], b[0], b[1]);
      asm volatile("s_waitcnt lgkmcnt(0)" ::: "memory");  // ds ops drained; vmem stays in flight
      __builtin_amdgcn_s_barrier();
      __builtin_amdgcn_sched_barrier(0);
    }
  }

  // epilogue: C/D layout col=lane&15, row=quad*4+reg
  #pragma unroll
  for (int nf = 0; nf < 4; nf++) {
    const int colg = (int)bnn + wn + nf * 16 + ml;
    const float bv = (colg < NBIAS) ? bias[colg] : 0.f;
    float s = 0.f, sq = 0.f;
    #pragma unroll
    for (int mf = 0; mf < 4; mf++) {
      #pragma unroll
      for (int i = 0; i < 4; i++) {
        const size_t rowg = bm + wm + mf * 16 + quad * 4 + i;
        float v = acc[mf][nf][i] + bv;
        if (RELU) v = fmaxf(v, 0.f);
        C[rowg * LDC + colg] = (bf16_t)v;
        if (STATS) {
          const bool ok = rowg < (size_t)Nvalid;
          s += ok ? v : 0.f;
          sq += ok ? v * v : 0.f;
        }
      }
    }
    if (STATS) {
      s += __shfl_down(s, 16);
      sq += __shfl_down(sq, 16);
      s += __shfl_down(s, 32);
      sq += __shfl_down(sq, 32);
      if (quad == 0) {
        atomicAdd(&sums[colg], s);
        atomicAdd(&sumsq[colg], sq);
      }
    }
  }
}

// ---------------- BN ----------------
__global__ void bn_params_kernel(const float* __restrict__ sums, const float* __restrict__ sumsq,
                                 const float* __restrict__ gamma, const float* __restrict__ beta,
                                 float* __restrict__ scale, float* __restrict__ shift, int N) {
  const int col = threadIdx.x;
  if (col >= 384) return;
  if (col >= 300) {  // pad cols: force transformed pad to 0
    scale[col] = 0.f;
    shift[col] = 0.f;
    return;
  }
  const float inv = 1.f / (float)N;
  const float mean = sums[col] * inv;
  float var = sumsq[col] * inv - mean * mean;
  if (var < 0.f) var = 0.f;
  const float sc = gamma[col] * rsqrtf(var + 1e-5f);
  scale[col] = sc;
  shift[col] = beta[col] - mean * sc;
}

// final-layer output: wave per node, lane<40 handles 8 cols, writes f32 out
__global__ void bn_apply_kernel(const bf16_t* __restrict__ H2, const float* __restrict__ scale,
                                const float* __restrict__ shift, float* __restrict__ out, int N) {
  const int w = (blockIdx.x * blockDim.x + threadIdx.x) >> 6;
  const int lane = threadIdx.x & 63;
  if (w >= N || lane >= 40) return;
  const int co = lane * 8;
  bf16x8 v8 = *(const bf16x8*)&H2[(size_t)w * 384 + co];
  f32x4 s0 = *(const f32x4*)&scale[co];
  f32x4 s1 = *(const f32x4*)&scale[co + 4];
  f32x4 t0 = *(const f32x4*)&shift[co];
  f32x4 t1 = *(const f32x4*)&shift[co + 4];
  #pragma unroll
  for (int j = 0; j < 8; j++) {
    float sc = (j < 4) ? s0[j] : s1[j - 4];
    float sh = (j < 4) ? t0[j] : t1[j - 4];
    float v = (float)v8[j] * sc + sh;
    if (co + j < 300) out[(size_t)w * 300 + co + j] = v;
  }
}

// ---------------- launch ----------------
extern "C" void kernel_launch(void* const* d_in, const int* in_sizes, int n_in,
                              void* d_out, int out_size, void* d_ws, size_t ws_size,
                              hipStream_t stream) {
  const int* x = (const int*)d_in[0];
  const int* ei = (const int*)d_in[1];
  const int* ea = (const int*)d_in[2];
  const float* xe1 = (const float*)d_in[3];
  const float* xe2 = (const float*)d_in[4];
  const float* ee1 = (const float*)d_in[5];
  const float* ee2 = (const float*)d_in[6];
  const float* w1 = (const float*)d_in[7];
  const float* b1 = (const float*)d_in[8];
  const float* w2 = (const float*)d_in[9];
  const float* b2 = (const float*)d_in[10];
  const float* gam = (const float*)d_in[11];
  const float* bet = (const float*)d_in[12];

  const int N = in_sizes[0] / 2;   // 100000
  const int E = in_sizes[1] / 2;   // 200000
  const int Mt = (N + 127) / 128;  // 782
  const size_t Mp = (size_t)Mt * 128;

  char* p = (char*)d_ws;
  auto take = [&](size_t b) -> char* {
    char* r = p;
    p += (b + 255) & ~(size_t)255;
    return r;
  };
  bf16_t* h    = (bf16_t*)take(Mp * 320 * 2);
  bf16_t* agg  = (bf16_t*)take(Mp * 320 * 2);
  bf16_t* C1   = (bf16_t*)take(Mp * 640 * 2);
  bf16_t* H2   = (bf16_t*)take(Mp * 384 * 2);
  bf16_t* W1bT = (bf16_t*)take((size_t)5 * 640 * 320 * 2);
  bf16_t* W2bT = (bf16_t*)take((size_t)5 * 384 * 640 * 2);
  bf16_t* T12  = (bf16_t*)take((size_t)5 * 21 * 320 * 2);
  int* deg     = (int*)take((size_t)N * 4);
  int* rowptr  = (int*)take((size_t)(N + 1) * 4);
  int* cursor  = (int*)take((size_t)N * 4);
  int* part    = (int*)take(1024 * 4);
  int* epack   = (int*)take((size_t)E * 4);
  float* sums  = (float*)take(384 * 4);
  float* sumsq = (float*)take(384 * 4);
  float* scale = (float*)take(384 * 4);
  float* shift = (float*)take(384 * 4);

  // agg pad rows must be exact zeros for GEMM1 (aggregate writes rows<N only)
  hipMemsetAsync(agg, 0, Mp * 320 * 2, stream);
  hipMemsetAsync(deg, 0, (size_t)N * 4, stream);

  const int nwb = (N + 3) / 4;  // wave-per-node kernels
  embed_kernel<<<nwb, 256, 0, stream>>>(x, xe1, xe2, h, N);

  count_deg_kernel<<<(E + 255) / 256, 256, 0, stream>>>(ei, deg, E);
  const int nsb = (N + 255) / 256;  // 391 (<=1024 for scan_block)
  scan_partial_kernel<<<nsb, 256, 0, stream>>>(deg, part, N);
  scan_block_kernel<<<1, 1024, 0, stream>>>(part, nsb);
  scan_final_kernel<<<nsb, 256, 0, stream>>>(deg, part, rowptr, cursor, N, E);
  fill_csr_kernel<<<(E + 255) / 256, 256, 0, stream>>>(ei, ea, cursor, epack, E);

  convert_w1_kernel<<<(5 * 640 * 320 + 255) / 256, 256, 0, stream>>>(w1, W1bT);
  convert_w2_kernel<<<(5 * 384 * 640 + 255) / 256, 256, 0, stream>>>(w2, W2bT);
  build_t12_kernel<<<(5 * 21 * 320 + 255) / 256, 256, 0, stream>>>(ee1, ee2, T12);

  const int nwg1 = Mt * 5;  // 3910
  const int nwg2 = Mt * 3;  // 2346
  const int nab = (N * 40 + 255) / 256;  // thread-centric aggregate grid

  for (int l = 0; l < 5; l++) {
    if (l == 0) {
      aggregate_kernel<false><<<nab, 256, 0, stream>>>(h, rowptr, epack,
                                                       T12 + (size_t)l * 21 * 320,
                                                       scale, shift, agg, N, 320);
    } else {
      aggregate_kernel<true><<<nab, 256, 0, stream>>>(H2, rowptr, epack,
                                                      T12 + (size_t)l * 21 * 320,
                                                      scale, shift, agg, N, 384);
    }
    // GEMM1: [Mp,320] x W1T[640,320] -> C1[Mp,640], bias b1 (600), ReLU
    gemm_kernel<320, 320, 640, 10, 5, 600, true, false>
        <<<nwg1, 256, 0, stream>>>(agg, W1bT + (size_t)l * 640 * 320,
                                   b1 + (size_t)l * 600, C1, sums, sumsq, N, nwg1);
    // zero stats before GEMM2's fused bn_stats epilogue
    hipMemsetAsync(sums, 0, 384 * 4, stream);
    hipMemsetAsync(sumsq, 0, 384 * 4, stream);
    // GEMM2: [Mp,640] x W2T[384,640] -> H2[Mp,384], bias b2 (300), fused col stats
    gemm_kernel<640, 640, 384, 20, 3, 300, false, true>
        <<<nwg2, 256, 0, stream>>>(C1, W2bT + (size_t)l * 384 * 640,
                                   b2 + (size_t)l * 300, H2, sums, sumsq, N, nwg2);
    bn_params_kernel<<<1, 384, 0, stream>>>(sums, sumsq, gam + (size_t)l * 300,
                                            bet + (size_t)l * 300, scale, shift, N);
  }
  // final layer output: BN(H2) -> f32 out
  bn_apply_kernel<<<nwb, 256, 0, stream>>>(H2, scale, shift, (float*)d_out, N);
}